// Round 3
// baseline (328.304 us; speedup 1.0000x reference)
//
#include <hip/hip_runtime.h>

// ---------------------------------------------------------------------------
// PatchFeatureExtractor: EdgeConv block
//   x:(4,4096,3) -> knn(k=20) -> f=(xj-xi, xi) -> conv6->64 BN ReLU
//   -> conv64->128 BN ReLU -> conv128->128 BN -> max over k -> (4,128,4096)
// R3: 16-pt blocks with 4-way wave channel split (weights 52 VGPR/wave),
//     k-split grids (2 planes when ws allows), BN folded into weights +
//     MFMA C-init, barriers 2/iter (main) 1/iter (stats2), stats1 replaced
//     by 7x7 second-moment kernel (channel-independent).
// ---------------------------------------------------------------------------

typedef __attribute__((ext_vector_type(8)))  short short8;
typedef __attribute__((ext_vector_type(4)))  float floatx4;

#define BATCH 4
#define NPTS  4096
#define KNN   20
#define BN_   (BATCH*NPTS)          // 16384 points
#define CNT   (BATCH*NPTS*KNN)      // 327680 positions

__device__ __forceinline__ unsigned short f2bf(float f) {
  unsigned u = __float_as_uint(f);
  unsigned r = u + 0x7FFFu + ((u >> 16) & 1u);   // RNE
  return (unsigned short)(r >> 16);
}

__device__ __forceinline__ short8 pack8(float a, float b, float c, float d,
                                        float e, float f, float g, float h) {
  short8 r;
  r[0]=(short)f2bf(a); r[1]=(short)f2bf(b); r[2]=(short)f2bf(c); r[3]=(short)f2bf(d);
  r[4]=(short)f2bf(e); r[5]=(short)f2bf(f); r[6]=(short)f2bf(g); r[7]=(short)f2bf(h);
  return r;
}

__device__ __forceinline__ unsigned mono(float f) {
  unsigned u = __float_as_uint(f);
  return u ^ ((unsigned)((int)u >> 31) | 0x80000000u);
}

// ------------------------------- K0 prep -----------------------------------
__global__ void pf_prep(const float* __restrict__ x, float4* __restrict__ xp,
                        float* __restrict__ stats) {
  int pt = blockIdx.x * 256 + threadIdx.x;      // grid 64 x 256 = 16384
  float x0 = x[pt*3+0], x1 = x[pt*3+1], x2 = x[pt*3+2];
  float xx = x0*x0 + x1*x1 + x2*x2;
  xp[pt] = make_float4(x0, x1, x2, xx);
  if (blockIdx.x == 0)
    for (int i = threadIdx.x; i < 640; i += 256) stats[i] = 0.0f;
}

// ------------------------------- K1 knn ------------------------------------
__device__ __forceinline__ float sort_take20th(float v, int lane) {
  #pragma unroll
  for (int k = 2; k <= 64; k <<= 1) {
    #pragma unroll
    for (int j = k >> 1; j >= 1; j >>= 1) {
      float o = __shfl_xor(v, j);
      bool keepmax = (((lane & j) == 0) == ((lane & k) == 0));
      v = keepmax ? fmaxf(v, o) : fminf(v, o);
    }
  }
  return __shfl(v, 19);   // descending sort: index 19 = 20th largest
}

__device__ __forceinline__ unsigned long long sort64_desc(unsigned long long v,
                                                          int lane) {
  #pragma unroll
  for (int k = 2; k <= 64; k <<= 1) {
    #pragma unroll
    for (int j = k >> 1; j >= 1; j >>= 1) {
      unsigned long long o = __shfl_xor(v, j);
      bool keepmax = (((lane & j) == 0) == ((lane & k) == 0));
      unsigned long long hi = v > o ? v : o;
      unsigned long long lo = v > o ? o : v;
      v = keepmax ? hi : lo;
    }
  }
  return v;   // lane r holds rank-r (descending)
}

__global__ __launch_bounds__(256) void pf_knn(const float4* __restrict__ xp,
                                              int* __restrict__ idxb) {
  __shared__ unsigned long long lst[8][128];   // 8 KB
  __shared__ int lcnt[8];
  const int tid  = threadIdx.x;
  const int lane = tid & 63;
  const int w    = tid >> 6;
  const int b    = blockIdx.x >> 9;                      // 512 blocks/batch
  const int nb   = (blockIdx.x & 511) * 8 + w * 2;       // 2 queries per wave
  const float4* xb = xp + b * NPTS;

  float4 q0 = xb[nb], q1 = xb[nb + 1];

  float mx0 = -3.0e38f, mx1 = -3.0e38f;
  for (int j0 = 0; j0 < NPTS; j0 += 64) {
    float4 c = xb[j0 + lane];
    float d0 = fmaf(q0.x,c.x, fmaf(q0.y,c.y, q0.z*c.z));
    float d1 = fmaf(q1.x,c.x, fmaf(q1.y,c.y, q1.z*c.z));
    mx0 = fmaxf(mx0, fmaf(2.f,d0,-q0.w) - c.w);
    mx1 = fmaxf(mx1, fmaf(2.f,d1,-q1.w) - c.w);
  }
  float T0 = sort_take20th(mx0, lane);
  float T1 = sort_take20th(mx1, lane);

  if (lane < 2) lcnt[w*2 + lane] = 0;
  __syncthreads();

  for (int j0 = 0; j0 < NPTS; j0 += 64) {
    float4 c = xb[j0 + lane];
    float d0 = fmaf(q0.x,c.x, fmaf(q0.y,c.y, q0.z*c.z));
    float d1 = fmaf(q1.x,c.x, fmaf(q1.y,c.y, q1.z*c.z));
    float p0 = fmaf(2.f,d0,-q0.w) - c.w;
    float p1 = fmaf(2.f,d1,-q1.w) - c.w;
    unsigned long long keybase = (unsigned long long)(4095 - (j0 + lane));
    if (p0 >= T0) {
      int o = atomicAdd(&lcnt[w*2+0], 1);
      if (o < 128) lst[w*2+0][o] = ((unsigned long long)mono(p0) << 32) | keybase;
    }
    if (p1 >= T1) {
      int o = atomicAdd(&lcnt[w*2+1], 1);
      if (o < 128) lst[w*2+1][o] = ((unsigned long long)mono(p1) << 32) | keybase;
    }
  }

  #pragma unroll 1
  for (int i = 0; i < 2; ++i) {
    const int li = w*2 + i;
    const int cn = lcnt[li];
    const int outbase = (b * NPTS + nb + i) * KNN;
    if (cn <= 64) {
      unsigned long long v = (lane < cn) ? lst[li][lane] : 0ull;
      v = sort64_desc(v, lane);
      if (lane < KNN) idxb[outbase + lane] = 4095 - (int)(v & 0xFFFFFFFFull);
    } else if (cn <= 128) {
      unsigned long long e0 = lst[li][lane];
      unsigned long long e1 = (lane + 64 < cn) ? lst[li][lane + 64] : 0ull;
      #pragma unroll 1
      for (int r = 0; r < KNN; ++r) {
        unsigned long long m = e0 > e1 ? e0 : e1;
        #pragma unroll
        for (int o = 32; o; o >>= 1) {
          unsigned long long t = __shfl_xor(m, o);
          m = t > m ? t : m;
        }
        if (lane == 0) idxb[outbase + r] = 4095 - (int)(m & 0xFFFFFFFFull);
        if (e0 == m) e0 = 0ull; else if (e1 == m) e1 = 0ull;
      }
    } else {
      const float4 qq = (i == 0) ? q0 : q1;
      unsigned long long prev = ~0ull;
      #pragma unroll 1
      for (int r = 0; r < KNN; ++r) {
        unsigned long long best = 0ull;
        for (int j0 = 0; j0 < NPTS; j0 += 64) {
          float4 c = xb[j0 + lane];
          float dd = fmaf(qq.x,c.x, fmaf(qq.y,c.y, qq.z*c.z));
          float pd = fmaf(2.f,dd,-qq.w) - c.w;
          unsigned long long key = ((unsigned long long)mono(pd) << 32) |
                                   (unsigned long long)(4095 - (j0 + lane));
          if (key < prev && key > best) best = key;
        }
        #pragma unroll
        for (int o = 32; o; o >>= 1) {
          unsigned long long t = __shfl_xor(best, o);
          best = t > best ? t : best;
        }
        if (lane == 0) idxb[outbase + r] = 4095 - (int)(best & 0xFFFFFFFFull);
        prev = best;
      }
    }
  }
}

// ------------------------------- K2 moments --------------------------------
// y1 = W1a.(xj-xi) + W1b.xi + b1 is linear in ft = (dx,dy,dz,x,y,z,1), so
// per-channel sum/sumsq of y1 follow from the 7x7 second-moment of ft:
// 6 first moments + 21 upper-tri products (27 sums, channel-independent).
__global__ __launch_bounds__(256) void pf_mom(
    const float4* __restrict__ xp, const int* __restrict__ idxb,
    float* __restrict__ mom) {
  __shared__ float M[27];
  const int tid = threadIdx.x;
  if (tid < 27) M[tid] = 0.f;
  __syncthreads();
  const int gid = blockIdx.x * 256 + tid;   // 128 blocks -> 32768 threads
  const int pt = gid >> 1;
  const int kk0 = (gid & 1) * 10;
  const float4 xi = xp[pt];
  const int ib = pt & ~(NPTS - 1);
  float a[27];
  #pragma unroll
  for (int i = 0; i < 27; ++i) a[i] = 0.f;
  #pragma unroll 1
  for (int u = 0; u < 10; ++u) {
    int j = idxb[pt*KNN + kk0 + u];
    float4 xj = xp[ib + j];
    float f[6] = {xj.x - xi.x, xj.y - xi.y, xj.z - xi.z, xi.x, xi.y, xi.z};
    int idx = 6;
    #pragma unroll
    for (int i1 = 0; i1 < 6; ++i1) {
      a[i1] += f[i1];
      #pragma unroll
      for (int i2 = i1; i2 < 6; ++i2) { a[idx] = fmaf(f[i1], f[i2], a[idx]); ++idx; }
    }
  }
  #pragma unroll
  for (int i = 0; i < 27; ++i) atomicAdd(&M[i], a[i]);
  __syncthreads();
  if (tid < 27) atomicAdd(&mom[tid], M[tid]);
}

// BN1 affine from moments: mean/var of y1_c as quadratic form in (W1_c, b1_c)
__global__ void pf_affine1m(const float* __restrict__ mom,
                            const float* __restrict__ W1, const float* __restrict__ b1,
                            const float* __restrict__ g1, const float* __restrict__ be1,
                            float* __restrict__ sc, float* __restrict__ sh) {
  int c = threadIdx.x;   // 64
  float wv[6];
  #pragma unroll
  for (int i = 0; i < 6; ++i) wv[i] = W1[c*6 + i];
  float b = b1[c];
  float S1 = b * (float)CNT;
  float Q  = b * b * (float)CNT;
  int idx = 6;
  #pragma unroll
  for (int i = 0; i < 6; ++i) {
    float m1 = mom[i];
    S1 += wv[i] * m1;
    Q  += 2.0f * b * wv[i] * m1;
    #pragma unroll
    for (int j = i; j < 6; ++j) {
      float coef = (i == j) ? 1.0f : 2.0f;
      Q += coef * wv[i] * wv[j] * mom[idx];
      ++idx;
    }
  }
  const float inv = 1.0f / (float)CNT;
  float mean = S1 * inv;
  float var  = Q * inv - mean * mean;
  float s = g1[c] * rsqrtf(var + 1e-5f);
  sc[c] = s;
  sh[c] = be1[c] - mean * s + s * b;      // b1 folded (downstream MFMA has no bias)
}

// ------------------------------- affine fold (BN2/BN3) ---------------------
__global__ void pf_affine(const float* __restrict__ gs, const float* __restrict__ gq,
                          const float* __restrict__ gamma, const float* __restrict__ beta,
                          const float* __restrict__ bconv, int foldb, int C,
                          float* __restrict__ sc, float* __restrict__ sh) {
  int c = threadIdx.x;
  if (c < C) {
    const float inv = 1.0f / (float)CNT;
    float mean = gs[c] * inv;
    float var  = gq[c] * inv - mean * mean;
    float s = gamma[c] * rsqrtf(var + 1e-5f);
    float shift = beta[c] - mean * s;
    if (foldb) shift = fmaf(s, bconv[c], shift);
    sc[c] = s; sh[c] = shift;
  }
}

// ------------------------------- K4 stats2 ---------------------------------
// 16 points/block; wave w: L1 out-ch [16w,16w+16), L2 out-ch [32w,32w+32).
// W1 pre-scaled by BN1, shift via MFMA C-init; W2 raw + b2 via C-init.
// 1 barrier/iter (H1+XJ double-buffered, XJ staged pre-barrier).
__global__ __launch_bounds__(256, 4) void pf_stats2(
    const float4* __restrict__ xp, const int* __restrict__ idxb,
    const float* __restrict__ W1, const float* __restrict__ sc1e,
    const float* __restrict__ sh1e, const float* __restrict__ W2,
    const float* __restrict__ b2, int kshift, int kpb,
    float* __restrict__ gs2, float* __restrict__ gq2) {
  __shared__ __align__(16) float4 XI[16];
  __shared__ __align__(16) float4 XJ[2][16];
  __shared__ __align__(16) unsigned short H1[2][16][72];
  __shared__ float SS[128], SQ[128];

  const int tid = threadIdx.x;
  const int lane = tid & 63, w = tid >> 6;
  const int l15 = lane & 15, quad = lane >> 4;
  const int pg = blockIdx.x >> kshift;
  const int ks0 = blockIdx.x & ((1 << kshift) - 1);
  const int kk0 = ks0 * kpb;
  const int pt0 = pg * 16;
  const int ib = pt0 & ~(NPTS - 1);

  if (tid < 128) { SS[tid] = 0.f; SQ[tid] = 0.f; }
  if (tid < 16) XI[tid] = xp[pt0 + tid];
  if (tid < 16) XJ[0][tid] = xp[ib + idxb[(pt0 + tid)*KNN + kk0]];

  const int c1 = 16*w + l15;
  const float s1 = sh1e[c1];
  short8 w1f = {0,0,0,0,0,0,0,0};
  {
    float a1 = sc1e[c1];
    if (quad == 0) {
      const float* p = W1 + c1*6;
      w1f = pack8(p[0]*a1,p[1]*a1,p[2]*a1,p[3]*a1,p[4]*a1,p[5]*a1,0.f,0.f);
    }
  }
  short8 w2f[2][2];
  float bb2[2];
  #pragma unroll
  for (int t = 0; t < 2; ++t) {
    int c = 32*w + 16*t + l15;
    bb2[t] = b2[c];
    #pragma unroll
    for (int ksl = 0; ksl < 2; ++ksl) {
      const float* p = W2 + c*64 + 32*ksl + quad*8;
      w2f[ksl][t] = pack8(p[0],p[1],p[2],p[3],p[4],p[5],p[6],p[7]);
    }
  }

  float sum[2] = {0,0}, sq[2] = {0,0};
  __syncthreads();

  for (int it = 0; it < kpb; ++it) {
    const int cur = it & 1;
    short8 af = {0,0,0,0,0,0,0,0};
    if (quad == 0) {
      float4 xi = XI[l15];
      float4 xj = XJ[cur][l15];
      af = pack8(xj.x-xi.x, xj.y-xi.y, xj.z-xi.z, xi.x, xi.y, xi.z, 0.f, 0.f);
    }
    if (tid < 16 && it + 1 < kpb)
      XJ[1-cur][tid] = xp[ib + idxb[(pt0 + tid)*KNN + kk0 + it + 1]];
    floatx4 acc1 = {s1, s1, s1, s1};
    acc1 = __builtin_amdgcn_mfma_f32_16x16x32_bf16(af, w1f, acc1, 0,0,0);
    #pragma unroll
    for (int r = 0; r < 4; ++r)
      H1[cur][quad*4 + r][c1] = f2bf(fmaxf(acc1[r], 0.f));
    __syncthreads();
    floatx4 acc2[2] = {{bb2[0],bb2[0],bb2[0],bb2[0]},
                       {bb2[1],bb2[1],bb2[1],bb2[1]}};
    #pragma unroll
    for (int ksl = 0; ksl < 2; ++ksl) {
      short8 a = *(const short8*)&H1[cur][l15][ksl*32 + quad*8];
      #pragma unroll
      for (int t = 0; t < 2; ++t)
        acc2[t] = __builtin_amdgcn_mfma_f32_16x16x32_bf16(a, w2f[ksl][t], acc2[t], 0,0,0);
    }
    #pragma unroll
    for (int t = 0; t < 2; ++t)
      #pragma unroll
      for (int r = 0; r < 4; ++r) {
        float v = acc2[t][r];
        sum[t] += v; sq[t] = fmaf(v, v, sq[t]);
      }
  }
  #pragma unroll
  for (int t = 0; t < 2; ++t) {
    float s = sum[t], z = sq[t];
    s += __shfl_xor(s, 16); z += __shfl_xor(z, 16);
    s += __shfl_xor(s, 32); z += __shfl_xor(z, 32);
    if (quad == 0) {
      int c = 32*w + 16*t + l15;
      atomicAdd(&SS[c], s); atomicAdd(&SQ[c], z);
    }
  }
  __syncthreads();
  if (tid < 128) { atomicAdd(&gs2[tid], SS[tid]); atomicAdd(&gq2[tid], SQ[tid]); }
}

// ------------------------------- K6 main -----------------------------------
// 16 points/block; wave w: L1 [16w,+16), L2/L3 [32w,+32). W1,W2 BN-scaled,
// shifts + b3 via MFMA C-init. 2 barriers/iter. Max written to per-split plane.
__global__ __launch_bounds__(256, 4) void pf_main(
    const float4* __restrict__ xp, const int* __restrict__ idxb,
    const float* __restrict__ W1, const float* __restrict__ sc1e,
    const float* __restrict__ sh1e, const float* __restrict__ W2,
    const float* __restrict__ sc2e, const float* __restrict__ shm2,
    const float* __restrict__ W3, const float* __restrict__ b3,
    int kshift, int kpb,
    float* __restrict__ gs3, float* __restrict__ gq3,
    float* __restrict__ maxv) {
  __shared__ __align__(16) float4 XI[16];
  __shared__ __align__(16) float4 XJ[2][16];
  __shared__ __align__(16) unsigned short H1[16][72];
  __shared__ __align__(16) unsigned short H2[16][136];
  __shared__ float SS[128], SQ[128];

  const int tid = threadIdx.x;
  const int lane = tid & 63, w = tid >> 6;
  const int l15 = lane & 15, quad = lane >> 4;
  const int pg = blockIdx.x >> kshift;
  const int ks0 = blockIdx.x & ((1 << kshift) - 1);
  const int kk0 = ks0 * kpb;
  const int pt0 = pg * 16;
  const int ib = pt0 & ~(NPTS - 1);

  if (tid < 128) { SS[tid] = 0.f; SQ[tid] = 0.f; }
  if (tid < 16) XI[tid] = xp[pt0 + tid];
  if (tid < 16) XJ[0][tid] = xp[ib + idxb[(pt0 + tid)*KNN + kk0]];

  const int c1 = 16*w + l15;
  const float s1 = sh1e[c1];
  short8 w1f = {0,0,0,0,0,0,0,0};
  {
    float a1 = sc1e[c1];
    if (quad == 0) {
      const float* p = W1 + c1*6;
      w1f = pack8(p[0]*a1,p[1]*a1,p[2]*a1,p[3]*a1,p[4]*a1,p[5]*a1,0.f,0.f);
    }
  }
  short8 w2f[2][2];
  float s2v[2];
  #pragma unroll
  for (int t = 0; t < 2; ++t) {
    int c = 32*w + 16*t + l15;
    float a2 = sc2e[c];
    s2v[t] = shm2[c];
    #pragma unroll
    for (int ksl = 0; ksl < 2; ++ksl) {
      const float* p = W2 + c*64 + 32*ksl + quad*8;
      w2f[ksl][t] = pack8(p[0]*a2,p[1]*a2,p[2]*a2,p[3]*a2,p[4]*a2,p[5]*a2,p[6]*a2,p[7]*a2);
    }
  }
  short8 w3f[4][2];
  float bb3[2];
  #pragma unroll
  for (int t = 0; t < 2; ++t) {
    int c = 32*w + 16*t + l15;
    bb3[t] = b3[c];
    #pragma unroll
    for (int ksl = 0; ksl < 4; ++ksl) {
      const float* p = W3 + c*128 + 32*ksl + quad*8;
      w3f[ksl][t] = pack8(p[0],p[1],p[2],p[3],p[4],p[5],p[6],p[7]);
    }
  }

  float sum[2] = {0,0}, sq[2] = {0,0};
  float mx[2][4];
  #pragma unroll
  for (int t = 0; t < 2; ++t)
    #pragma unroll
    for (int r = 0; r < 4; ++r) mx[t][r] = -3.0e38f;

  __syncthreads();

  for (int it = 0; it < kpb; ++it) {
    const int cur = it & 1;
    short8 af = {0,0,0,0,0,0,0,0};
    if (quad == 0) {
      float4 xi = XI[l15];
      float4 xj = XJ[cur][l15];
      af = pack8(xj.x-xi.x, xj.y-xi.y, xj.z-xi.z, xi.x, xi.y, xi.z, 0.f, 0.f);
    }
    if (tid < 16 && it + 1 < kpb)
      XJ[1-cur][tid] = xp[ib + idxb[(pt0 + tid)*KNN + kk0 + it + 1]];
    floatx4 acc1 = {s1, s1, s1, s1};
    acc1 = __builtin_amdgcn_mfma_f32_16x16x32_bf16(af, w1f, acc1, 0,0,0);
    #pragma unroll
    for (int r = 0; r < 4; ++r)
      H1[quad*4 + r][c1] = f2bf(fmaxf(acc1[r], 0.f));
    __syncthreads();                     // A: H1 ready (XJ[next] staged)
    floatx4 acc2[2] = {{s2v[0],s2v[0],s2v[0],s2v[0]},
                       {s2v[1],s2v[1],s2v[1],s2v[1]}};
    #pragma unroll
    for (int ksl = 0; ksl < 2; ++ksl) {
      short8 a = *(const short8*)&H1[l15][ksl*32 + quad*8];
      #pragma unroll
      for (int t = 0; t < 2; ++t)
        acc2[t] = __builtin_amdgcn_mfma_f32_16x16x32_bf16(a, w2f[ksl][t], acc2[t], 0,0,0);
    }
    #pragma unroll
    for (int t = 0; t < 2; ++t) {
      int c = 32*w + 16*t + l15;
      #pragma unroll
      for (int r = 0; r < 4; ++r)
        H2[quad*4 + r][c] = f2bf(fmaxf(acc2[t][r], 0.f));
    }
    __syncthreads();                     // B: H2 ready
    floatx4 acc3[2] = {{bb3[0],bb3[0],bb3[0],bb3[0]},
                       {bb3[1],bb3[1],bb3[1],bb3[1]}};
    #pragma unroll
    for (int ksl = 0; ksl < 4; ++ksl) {
      short8 a = *(const short8*)&H2[l15][ksl*32 + quad*8];
      #pragma unroll
      for (int t = 0; t < 2; ++t)
        acc3[t] = __builtin_amdgcn_mfma_f32_16x16x32_bf16(a, w3f[ksl][t], acc3[t], 0,0,0);
    }
    #pragma unroll
    for (int t = 0; t < 2; ++t)
      #pragma unroll
      for (int r = 0; r < 4; ++r) {
        float v = acc3[t][r];
        sum[t] += v; sq[t] = fmaf(v, v, sq[t]);
        mx[t][r] = fmaxf(mx[t][r], v);
      }
  }
  float* mp = maxv + (size_t)ks0 * BN_ * 128;
  #pragma unroll
  for (int t = 0; t < 2; ++t) {
    int c = 32*w + 16*t + l15;
    #pragma unroll
    for (int r = 0; r < 4; ++r)
      mp[(pt0 + quad*4 + r)*128 + c] = mx[t][r];
  }
  #pragma unroll
  for (int t = 0; t < 2; ++t) {
    float s = sum[t], z = sq[t];
    s += __shfl_xor(s, 16); z += __shfl_xor(z, 16);
    s += __shfl_xor(s, 32); z += __shfl_xor(z, 32);
    if (quad == 0) {
      int c = 32*w + 16*t + l15;
      atomicAdd(&SS[c], s); atomicAdd(&SQ[c], z);
    }
  }
  __syncthreads();
  if (tid < 128) { atomicAdd(&gs3[tid], SS[tid]); atomicAdd(&gq3[tid], SQ[tid]); }
}

// ------------------------------- K8 output ---------------------------------
__global__ __launch_bounds__(256) void pf_out(
    const float* __restrict__ maxv, int nspl,
    const float* __restrict__ sc3, const float* __restrict__ sh3,
    float* __restrict__ out) {
  __shared__ float T[128][65];
  __shared__ float SC[128], SH[128];
  const int tid = threadIdx.x;
  const int b  = blockIdx.x >> 6;
  const int n0 = (blockIdx.x & 63) * 64;
  if (tid < 128) { SC[tid] = sc3[tid]; SH[tid] = sh3[tid]; }
  __syncthreads();
  const float4* mv4 = (const float4*)maxv;
  #pragma unroll
  for (int r = 0; r < 8; ++r) {
    int fid = r * 256 + tid;
    int nl = fid >> 5, c4 = fid & 31;
    float4 v = mv4[(b*NPTS + n0 + nl)*32 + c4];
    if (nspl == 2) {
      float4 v2 = mv4[524288 + (b*NPTS + n0 + nl)*32 + c4];   // BN_*128/4
      v.x = fmaxf(v.x, v2.x); v.y = fmaxf(v.y, v2.y);
      v.z = fmaxf(v.z, v2.z); v.w = fmaxf(v.w, v2.w);
    }
    int c = c4 * 4;
    T[c+0][nl] = fmaf(SC[c+0], v.x, SH[c+0]);
    T[c+1][nl] = fmaf(SC[c+1], v.y, SH[c+1]);
    T[c+2][nl] = fmaf(SC[c+2], v.z, SH[c+2]);
    T[c+3][nl] = fmaf(SC[c+3], v.w, SH[c+3]);
  }
  __syncthreads();
  #pragma unroll
  for (int r = 0; r < 8; ++r) {
    int fid = r * 256 + tid;
    int c = fid >> 4, nq = fid & 15;
    float4 o;
    o.x = T[c][nq*4+0]; o.y = T[c][nq*4+1];
    o.z = T[c][nq*4+2]; o.w = T[c][nq*4+3];
    *(float4*)(out + (size_t)b*128*NPTS + (size_t)c*NPTS + n0 + nq*4) = o;
  }
}

// ------------------------------- launcher ----------------------------------
extern "C" void kernel_launch(void* const* d_in, const int* in_sizes, int n_in,
                              void* d_out, int out_size, void* d_ws, size_t ws_size,
                              hipStream_t stream) {
  const float* x   = (const float*)d_in[0];
  const float* W1  = (const float*)d_in[1];
  const float* b1  = (const float*)d_in[2];
  const float* g1  = (const float*)d_in[3];
  const float* be1 = (const float*)d_in[4];
  const float* W2  = (const float*)d_in[5];
  const float* b2  = (const float*)d_in[6];
  const float* g2  = (const float*)d_in[7];
  const float* be2 = (const float*)d_in[8];
  const float* W3  = (const float*)d_in[9];
  const float* b3  = (const float*)d_in[10];
  const float* g3  = (const float*)d_in[11];
  const float* be3 = (const float*)d_in[12];
  float* out = (float*)d_out;

  char* p = (char*)d_ws;
  float4* xp   = (float4*)(p);                      // 262144 B
  int*    idxb = (int*)(p + 262144);                // 1310720 B
  float*  stats= (float*)(p + 1573864 - 1000);      // keep simple below
  // recompute offsets cleanly:
  stats        = (float*)(p + 262144 + 1310720);    // 2560 B
  float*  aff  = (float*)(p + 262144 + 1310720 + 2560);  // 2560 B
  float*  maxv = (float*)(p + 262144 + 1310720 + 2560 + 2560);

  const size_t plane = (size_t)BN_ * 128 * 4;       // 8 MB
  const size_t base  = 262144 + 1310720 + 2560 + 2560;
  const int nspl  = (ws_size >= base + 2 * plane) ? 2 : 1;
  const int kshift = nspl - 1;
  const int kpb    = KNN / nspl;

  float *mom = stats;                              // 27 floats
  float *gs2 = stats + 128, *gq2 = stats + 256;
  float *gs3 = stats + 384, *gq3 = stats + 512;
  float *sc1e = aff,        *sh1e = aff + 64;
  float *sc2e = aff + 128,  *shm2 = aff + 256;
  float *sc3  = aff + 384,  *sh3  = aff + 512;

  pf_prep    <<<64,   256, 0, stream>>>(x, xp, stats);
  pf_knn     <<<2048, 256, 0, stream>>>(xp, idxb);
  pf_mom     <<<128,  256, 0, stream>>>(xp, idxb, mom);
  pf_affine1m<<<1,    64,  0, stream>>>(mom, W1, b1, g1, be1, sc1e, sh1e);
  pf_stats2  <<<1024*nspl, 256, 0, stream>>>(xp, idxb, W1, sc1e, sh1e, W2, b2,
                                             kshift, kpb, gs2, gq2);
  pf_affine  <<<1,    128, 0, stream>>>(gs2, gq2, g2, be2, b2, 1, 128, sc2e, shm2);
  pf_main    <<<1024*nspl, 256, 0, stream>>>(xp, idxb, W1, sc1e, sh1e, W2, sc2e, shm2,
                                             W3, b3, kshift, kpb, gs3, gq3, maxv);
  pf_affine  <<<1,    128, 0, stream>>>(gs3, gq3, g3, be3, b3, 0, 128, sc3, sh3);
  pf_out     <<<256,  256, 0, stream>>>(maxv, nspl, sc3, sh3, out);
}

// Round 4
// 277.972 us; speedup vs baseline: 1.1811x; 1.1811x over previous
//
#include <hip/hip_runtime.h>

// ---------------------------------------------------------------------------
// PatchFeatureExtractor: EdgeConv block
//   x:(4,4096,3) -> knn(k=20) -> f=(xj-xi, xi) -> conv6->64 BN ReLU
//   -> conv64->128 BN ReLU -> conv128->128 BN -> max over k -> (4,128,4096)
// R4: weight fragments PRE-PACKED to global (1 coalesced b128 load each,
//     replacing ~100 scattered loads + ~500 VALU per block) ; no k-split
//     (grid 1024 x 16-pt blocks, 20 iters, single maxv plane).
// ---------------------------------------------------------------------------

typedef __attribute__((ext_vector_type(8)))  short short8;
typedef __attribute__((ext_vector_type(4)))  float floatx4;

#define BATCH 4
#define NPTS  4096
#define KNN   20
#define BN_   (BATCH*NPTS)          // 16384 points
#define CNT   (BATCH*NPTS*KNN)      // 327680 positions

__device__ __forceinline__ unsigned short f2bf(float f) {
  unsigned u = __float_as_uint(f);
  unsigned r = u + 0x7FFFu + ((u >> 16) & 1u);   // RNE
  return (unsigned short)(r >> 16);
}

__device__ __forceinline__ short8 pack8(float a, float b, float c, float d,
                                        float e, float f, float g, float h) {
  short8 r;
  r[0]=(short)f2bf(a); r[1]=(short)f2bf(b); r[2]=(short)f2bf(c); r[3]=(short)f2bf(d);
  r[4]=(short)f2bf(e); r[5]=(short)f2bf(f); r[6]=(short)f2bf(g); r[7]=(short)f2bf(h);
  return r;
}

__device__ __forceinline__ unsigned mono(float f) {
  unsigned u = __float_as_uint(f);
  return u ^ ((unsigned)((int)u >> 31) | 0x80000000u);
}

// ------------------------------- K0 prep -----------------------------------
__global__ void pf_prep(const float* __restrict__ x, float4* __restrict__ xp,
                        float* __restrict__ stats) {
  int pt = blockIdx.x * 256 + threadIdx.x;      // grid 64 x 256 = 16384
  float x0 = x[pt*3+0], x1 = x[pt*3+1], x2 = x[pt*3+2];
  float xx = x0*x0 + x1*x1 + x2*x2;
  xp[pt] = make_float4(x0, x1, x2, xx);
  if (blockIdx.x == 0)
    for (int i = threadIdx.x; i < 640; i += 256) stats[i] = 0.0f;
}

// ------------------------------- K1 knn ------------------------------------
__device__ __forceinline__ float sort_take20th(float v, int lane) {
  #pragma unroll
  for (int k = 2; k <= 64; k <<= 1) {
    #pragma unroll
    for (int j = k >> 1; j >= 1; j >>= 1) {
      float o = __shfl_xor(v, j);
      bool keepmax = (((lane & j) == 0) == ((lane & k) == 0));
      v = keepmax ? fmaxf(v, o) : fminf(v, o);
    }
  }
  return __shfl(v, 19);   // descending sort: index 19 = 20th largest
}

__device__ __forceinline__ unsigned long long sort64_desc(unsigned long long v,
                                                          int lane) {
  #pragma unroll
  for (int k = 2; k <= 64; k <<= 1) {
    #pragma unroll
    for (int j = k >> 1; j >= 1; j >>= 1) {
      unsigned long long o = __shfl_xor(v, j);
      bool keepmax = (((lane & j) == 0) == ((lane & k) == 0));
      unsigned long long hi = v > o ? v : o;
      unsigned long long lo = v > o ? o : v;
      v = keepmax ? hi : lo;
    }
  }
  return v;   // lane r holds rank-r (descending)
}

__global__ __launch_bounds__(256) void pf_knn(const float4* __restrict__ xp,
                                              int* __restrict__ idxb) {
  __shared__ unsigned long long lst[8][128];   // 8 KB
  __shared__ int lcnt[8];
  const int tid  = threadIdx.x;
  const int lane = tid & 63;
  const int w    = tid >> 6;
  const int b    = blockIdx.x >> 9;                      // 512 blocks/batch
  const int nb   = (blockIdx.x & 511) * 8 + w * 2;       // 2 queries per wave
  const float4* xb = xp + b * NPTS;

  float4 q0 = xb[nb], q1 = xb[nb + 1];

  float mx0 = -3.0e38f, mx1 = -3.0e38f;
  for (int j0 = 0; j0 < NPTS; j0 += 64) {
    float4 c = xb[j0 + lane];
    float d0 = fmaf(q0.x,c.x, fmaf(q0.y,c.y, q0.z*c.z));
    float d1 = fmaf(q1.x,c.x, fmaf(q1.y,c.y, q1.z*c.z));
    mx0 = fmaxf(mx0, fmaf(2.f,d0,-q0.w) - c.w);
    mx1 = fmaxf(mx1, fmaf(2.f,d1,-q1.w) - c.w);
  }
  float T0 = sort_take20th(mx0, lane);
  float T1 = sort_take20th(mx1, lane);

  if (lane < 2) lcnt[w*2 + lane] = 0;
  __syncthreads();

  for (int j0 = 0; j0 < NPTS; j0 += 64) {
    float4 c = xb[j0 + lane];
    float d0 = fmaf(q0.x,c.x, fmaf(q0.y,c.y, q0.z*c.z));
    float d1 = fmaf(q1.x,c.x, fmaf(q1.y,c.y, q1.z*c.z));
    float p0 = fmaf(2.f,d0,-q0.w) - c.w;
    float p1 = fmaf(2.f,d1,-q1.w) - c.w;
    unsigned long long keybase = (unsigned long long)(4095 - (j0 + lane));
    if (p0 >= T0) {
      int o = atomicAdd(&lcnt[w*2+0], 1);
      if (o < 128) lst[w*2+0][o] = ((unsigned long long)mono(p0) << 32) | keybase;
    }
    if (p1 >= T1) {
      int o = atomicAdd(&lcnt[w*2+1], 1);
      if (o < 128) lst[w*2+1][o] = ((unsigned long long)mono(p1) << 32) | keybase;
    }
  }

  #pragma unroll 1
  for (int i = 0; i < 2; ++i) {
    const int li = w*2 + i;
    const int cn = lcnt[li];
    const int outbase = (b * NPTS + nb + i) * KNN;
    if (cn <= 64) {
      unsigned long long v = (lane < cn) ? lst[li][lane] : 0ull;
      v = sort64_desc(v, lane);
      if (lane < KNN) idxb[outbase + lane] = 4095 - (int)(v & 0xFFFFFFFFull);
    } else if (cn <= 128) {
      unsigned long long e0 = lst[li][lane];
      unsigned long long e1 = (lane + 64 < cn) ? lst[li][lane + 64] : 0ull;
      #pragma unroll 1
      for (int r = 0; r < KNN; ++r) {
        unsigned long long m = e0 > e1 ? e0 : e1;
        #pragma unroll
        for (int o = 32; o; o >>= 1) {
          unsigned long long t = __shfl_xor(m, o);
          m = t > m ? t : m;
        }
        if (lane == 0) idxb[outbase + r] = 4095 - (int)(m & 0xFFFFFFFFull);
        if (e0 == m) e0 = 0ull; else if (e1 == m) e1 = 0ull;
      }
    } else {
      const float4 qq = (i == 0) ? q0 : q1;
      unsigned long long prev = ~0ull;
      #pragma unroll 1
      for (int r = 0; r < KNN; ++r) {
        unsigned long long best = 0ull;
        for (int j0 = 0; j0 < NPTS; j0 += 64) {
          float4 c = xb[j0 + lane];
          float dd = fmaf(qq.x,c.x, fmaf(qq.y,c.y, qq.z*c.z));
          float pd = fmaf(2.f,dd,-qq.w) - c.w;
          unsigned long long key = ((unsigned long long)mono(pd) << 32) |
                                   (unsigned long long)(4095 - (j0 + lane));
          if (key < prev && key > best) best = key;
        }
        #pragma unroll
        for (int o = 32; o; o >>= 1) {
          unsigned long long t = __shfl_xor(best, o);
          best = t > best ? t : best;
        }
        if (lane == 0) idxb[outbase + r] = 4095 - (int)(best & 0xFFFFFFFFull);
        prev = best;
      }
    }
  }
}

// ------------------------------- K2 moments --------------------------------
__global__ __launch_bounds__(256) void pf_mom(
    const float4* __restrict__ xp, const int* __restrict__ idxb,
    float* __restrict__ mom) {
  __shared__ float M[27];
  const int tid = threadIdx.x;
  if (tid < 27) M[tid] = 0.f;
  __syncthreads();
  const int gid = blockIdx.x * 256 + tid;   // 128 blocks -> 32768 threads
  const int pt = gid >> 1;
  const int kk0 = (gid & 1) * 10;
  const float4 xi = xp[pt];
  const int ib = pt & ~(NPTS - 1);
  float a[27];
  #pragma unroll
  for (int i = 0; i < 27; ++i) a[i] = 0.f;
  #pragma unroll 1
  for (int u = 0; u < 10; ++u) {
    int j = idxb[pt*KNN + kk0 + u];
    float4 xj = xp[ib + j];
    float f[6] = {xj.x - xi.x, xj.y - xi.y, xj.z - xi.z, xi.x, xi.y, xi.z};
    int idx = 6;
    #pragma unroll
    for (int i1 = 0; i1 < 6; ++i1) {
      a[i1] += f[i1];
      #pragma unroll
      for (int i2 = i1; i2 < 6; ++i2) { a[idx] = fmaf(f[i1], f[i2], a[idx]); ++idx; }
    }
  }
  #pragma unroll
  for (int i = 0; i < 27; ++i) atomicAdd(&M[i], a[i]);
  __syncthreads();
  if (tid < 27) atomicAdd(&mom[tid], M[tid]);
}

// BN1 affine from moments
__global__ void pf_affine1m(const float* __restrict__ mom,
                            const float* __restrict__ W1, const float* __restrict__ b1,
                            const float* __restrict__ g1, const float* __restrict__ be1,
                            float* __restrict__ sc, float* __restrict__ sh) {
  int c = threadIdx.x;   // 64
  float wv[6];
  #pragma unroll
  for (int i = 0; i < 6; ++i) wv[i] = W1[c*6 + i];
  float b = b1[c];
  float S1 = b * (float)CNT;
  float Q  = b * b * (float)CNT;
  int idx = 6;
  #pragma unroll
  for (int i = 0; i < 6; ++i) {
    float m1 = mom[i];
    S1 += wv[i] * m1;
    Q  += 2.0f * b * wv[i] * m1;
    #pragma unroll
    for (int j = i; j < 6; ++j) {
      float coef = (i == j) ? 1.0f : 2.0f;
      Q += coef * wv[i] * wv[j] * mom[idx];
      ++idx;
    }
  }
  const float inv = 1.0f / (float)CNT;
  float mean = S1 * inv;
  float var  = Q * inv - mean * mean;
  float s = g1[c] * rsqrtf(var + 1e-5f);
  sc[c] = s;
  sh[c] = be1[c] - mean * s + s * b;
}

// ------------------------------- affine fold (BN2/BN3) ---------------------
__global__ void pf_affine(const float* __restrict__ gs, const float* __restrict__ gq,
                          const float* __restrict__ gamma, const float* __restrict__ beta,
                          const float* __restrict__ bconv, int foldb, int C,
                          float* __restrict__ sc, float* __restrict__ sh) {
  int c = threadIdx.x;
  if (c < C) {
    const float inv = 1.0f / (float)CNT;
    float mean = gs[c] * inv;
    float var  = gq[c] * inv - mean * mean;
    float s = gamma[c] * rsqrtf(var + 1e-5f);
    float shift = beta[c] - mean * s;
    if (foldb) shift = fmaf(s, bconv[c], shift);
    sc[c] = s; sh[c] = shift;
  }
}

// ------------------------------- weight pre-pack ---------------------------
// Fragment slots (64 lanes x short8 = 1KB each):
//   0..3   : W1*sc1   B-frag, ch-tile t, k<6 (zero-padded)
//   4..19  : W2 raw   (ntile 0..7) x (kslice 0..1), slot = 4 + ntile*2 + ks
//   20..35 : W2*sc2   same indexing + 16
//   36..67 : W3 raw   (ntile 0..7) x (kslice 0..3), slot = 36 + ntile*4 + ks
// B-frag element (lane = quad*16+l15, reg j): B[k=quad*8+j][n=l15].
__global__ void pf_pack(const float* __restrict__ W1, const float* __restrict__ sc1,
                        const float* __restrict__ W2, const float* __restrict__ sc2,
                        const float* __restrict__ W3, int phase,
                        unsigned short* __restrict__ wpk) {
  const int lane = threadIdx.x;         // 64
  const int l15 = lane & 15, quad = lane >> 4;
  int slot;
  if (phase == 1) slot = 20 + blockIdx.x;                       // grid 16
  else slot = (blockIdx.x < 20) ? blockIdx.x : blockIdx.x + 16; // grid 52
  short8 r;
  #pragma unroll
  for (int j = 0; j < 8; ++j) {
    int k = quad*8 + j;
    float val = 0.f;
    if (slot < 4) {
      int c = 16*slot + l15;
      if (k < 6) val = W1[c*6 + k] * sc1[c];
    } else if (slot < 20) {
      int s = slot - 4;  int c = 16*(s>>1) + l15;
      val = W2[c*64 + 32*(s&1) + k];
    } else if (slot < 36) {
      int s = slot - 20; int c = 16*(s>>1) + l15;
      val = W2[c*64 + 32*(s&1) + k] * sc2[c];
    } else {
      int s = slot - 36; int c = 16*(s>>2) + l15;
      val = W3[c*128 + 32*(s&3) + k];
    }
    r[j] = (short)f2bf(val);
  }
  ((short8*)wpk)[slot*64 + lane] = r;
}

// ------------------------------- K4 stats2 ---------------------------------
// 16 points/block; wave w: L1 out-ch [16w,+16), L2 out-ch [32w,+32).
__global__ __launch_bounds__(256, 4) void pf_stats2(
    const float4* __restrict__ xp, const int* __restrict__ idxb,
    const unsigned short* __restrict__ wpk,
    const float* __restrict__ sh1e, const float* __restrict__ b2,
    float* __restrict__ gs2, float* __restrict__ gq2) {
  __shared__ __align__(16) float4 XI[16];
  __shared__ __align__(16) float4 XJ[2][16];
  __shared__ __align__(16) unsigned short H1[2][16][72];
  __shared__ float SS[128], SQ[128];

  const int tid = threadIdx.x;
  const int lane = tid & 63, w = tid >> 6;
  const int l15 = lane & 15, quad = lane >> 4;
  const int pt0 = blockIdx.x * 16;
  const int ib = pt0 & ~(NPTS - 1);

  if (tid < 128) { SS[tid] = 0.f; SQ[tid] = 0.f; }
  if (tid < 16) XI[tid] = xp[pt0 + tid];
  if (tid < 16) XJ[0][tid] = xp[ib + idxb[(pt0 + tid)*KNN]];

  const short8* wq = (const short8*)wpk;
  const int c1 = 16*w + l15;
  const float s1 = sh1e[c1];
  short8 w1f = wq[w*64 + lane];
  short8 w2f[2][2];
  float bb2[2];
  #pragma unroll
  for (int t = 0; t < 2; ++t) {
    bb2[t] = b2[32*w + 16*t + l15];
    #pragma unroll
    for (int ks = 0; ks < 2; ++ks)
      w2f[ks][t] = wq[(4 + (2*w+t)*2 + ks)*64 + lane];
  }

  float sum[2] = {0,0}, sq[2] = {0,0};
  __syncthreads();

  for (int it = 0; it < KNN; ++it) {
    const int cur = it & 1;
    short8 af = {0,0,0,0,0,0,0,0};
    if (quad == 0) {
      float4 xi = XI[l15];
      float4 xj = XJ[cur][l15];
      af = pack8(xj.x-xi.x, xj.y-xi.y, xj.z-xi.z, xi.x, xi.y, xi.z, 0.f, 0.f);
    }
    if (tid < 16 && it + 1 < KNN)
      XJ[1-cur][tid] = xp[ib + idxb[(pt0 + tid)*KNN + it + 1]];
    floatx4 acc1 = {s1, s1, s1, s1};
    acc1 = __builtin_amdgcn_mfma_f32_16x16x32_bf16(af, w1f, acc1, 0,0,0);
    #pragma unroll
    for (int r = 0; r < 4; ++r)
      H1[cur][quad*4 + r][c1] = f2bf(fmaxf(acc1[r], 0.f));
    __syncthreads();
    floatx4 acc2[2] = {{bb2[0],bb2[0],bb2[0],bb2[0]},
                       {bb2[1],bb2[1],bb2[1],bb2[1]}};
    #pragma unroll
    for (int ks = 0; ks < 2; ++ks) {
      short8 a = *(const short8*)&H1[cur][l15][ks*32 + quad*8];
      #pragma unroll
      for (int t = 0; t < 2; ++t)
        acc2[t] = __builtin_amdgcn_mfma_f32_16x16x32_bf16(a, w2f[ks][t], acc2[t], 0,0,0);
    }
    #pragma unroll
    for (int t = 0; t < 2; ++t)
      #pragma unroll
      for (int r = 0; r < 4; ++r) {
        float v = acc2[t][r];
        sum[t] += v; sq[t] = fmaf(v, v, sq[t]);
      }
  }
  #pragma unroll
  for (int t = 0; t < 2; ++t) {
    float s = sum[t], z = sq[t];
    s += __shfl_xor(s, 16); z += __shfl_xor(z, 16);
    s += __shfl_xor(s, 32); z += __shfl_xor(z, 32);
    if (quad == 0) {
      int c = 32*w + 16*t + l15;
      atomicAdd(&SS[c], s); atomicAdd(&SQ[c], z);
    }
  }
  __syncthreads();
  if (tid < 128) { atomicAdd(&gs2[tid], SS[tid]); atomicAdd(&gq2[tid], SQ[tid]); }
}

// ------------------------------- K6 main -----------------------------------
__global__ __launch_bounds__(256, 4) void pf_main(
    const float4* __restrict__ xp, const int* __restrict__ idxb,
    const unsigned short* __restrict__ wpk,
    const float* __restrict__ sh1e, const float* __restrict__ shm2,
    const float* __restrict__ b3,
    float* __restrict__ gs3, float* __restrict__ gq3,
    float* __restrict__ maxv) {
  __shared__ __align__(16) float4 XI[16];
  __shared__ __align__(16) float4 XJ[2][16];
  __shared__ __align__(16) unsigned short H1[16][72];
  __shared__ __align__(16) unsigned short H2[16][136];
  __shared__ float SS[128], SQ[128];

  const int tid = threadIdx.x;
  const int lane = tid & 63, w = tid >> 6;
  const int l15 = lane & 15, quad = lane >> 4;
  const int pt0 = blockIdx.x * 16;
  const int ib = pt0 & ~(NPTS - 1);

  if (tid < 128) { SS[tid] = 0.f; SQ[tid] = 0.f; }
  if (tid < 16) XI[tid] = xp[pt0 + tid];
  if (tid < 16) XJ[0][tid] = xp[ib + idxb[(pt0 + tid)*KNN]];

  const short8* wq = (const short8*)wpk;
  const int c1 = 16*w + l15;
  const float s1 = sh1e[c1];
  short8 w1f = wq[w*64 + lane];
  short8 w2f[2][2];
  float s2v[2], bb3[2];
  #pragma unroll
  for (int t = 0; t < 2; ++t) {
    int c = 32*w + 16*t + l15;
    s2v[t] = shm2[c]; bb3[t] = b3[c];
    #pragma unroll
    for (int ks = 0; ks < 2; ++ks)
      w2f[ks][t] = wq[(20 + (2*w+t)*2 + ks)*64 + lane];
  }
  short8 w3f[4][2];
  #pragma unroll
  for (int t = 0; t < 2; ++t)
    #pragma unroll
    for (int ks = 0; ks < 4; ++ks)
      w3f[ks][t] = wq[(36 + (2*w+t)*4 + ks)*64 + lane];

  float sum[2] = {0,0}, sq[2] = {0,0};
  float mx[2][4];
  #pragma unroll
  for (int t = 0; t < 2; ++t)
    #pragma unroll
    for (int r = 0; r < 4; ++r) mx[t][r] = -3.0e38f;

  __syncthreads();

  for (int it = 0; it < KNN; ++it) {
    const int cur = it & 1;
    short8 af = {0,0,0,0,0,0,0,0};
    if (quad == 0) {
      float4 xi = XI[l15];
      float4 xj = XJ[cur][l15];
      af = pack8(xj.x-xi.x, xj.y-xi.y, xj.z-xi.z, xi.x, xi.y, xi.z, 0.f, 0.f);
    }
    if (tid < 16 && it + 1 < KNN)
      XJ[1-cur][tid] = xp[ib + idxb[(pt0 + tid)*KNN + it + 1]];
    floatx4 acc1 = {s1, s1, s1, s1};
    acc1 = __builtin_amdgcn_mfma_f32_16x16x32_bf16(af, w1f, acc1, 0,0,0);
    #pragma unroll
    for (int r = 0; r < 4; ++r)
      H1[quad*4 + r][c1] = f2bf(fmaxf(acc1[r], 0.f));
    __syncthreads();                     // A: H1 ready (XJ[next] staged)
    floatx4 acc2[2] = {{s2v[0],s2v[0],s2v[0],s2v[0]},
                       {s2v[1],s2v[1],s2v[1],s2v[1]}};
    #pragma unroll
    for (int ks = 0; ks < 2; ++ks) {
      short8 a = *(const short8*)&H1[l15][ks*32 + quad*8];
      #pragma unroll
      for (int t = 0; t < 2; ++t)
        acc2[t] = __builtin_amdgcn_mfma_f32_16x16x32_bf16(a, w2f[ks][t], acc2[t], 0,0,0);
    }
    #pragma unroll
    for (int t = 0; t < 2; ++t) {
      int c = 32*w + 16*t + l15;
      #pragma unroll
      for (int r = 0; r < 4; ++r)
        H2[quad*4 + r][c] = f2bf(fmaxf(acc2[t][r], 0.f));
    }
    __syncthreads();                     // B: H2 ready
    floatx4 acc3[2] = {{bb3[0],bb3[0],bb3[0],bb3[0]},
                       {bb3[1],bb3[1],bb3[1],bb3[1]}};
    #pragma unroll
    for (int ks = 0; ks < 4; ++ks) {
      short8 a = *(const short8*)&H2[l15][ks*32 + quad*8];
      #pragma unroll
      for (int t = 0; t < 2; ++t)
        acc3[t] = __builtin_amdgcn_mfma_f32_16x16x32_bf16(a, w3f[ks][t], acc3[t], 0,0,0);
    }
    #pragma unroll
    for (int t = 0; t < 2; ++t)
      #pragma unroll
      for (int r = 0; r < 4; ++r) {
        float v = acc3[t][r];
        sum[t] += v; sq[t] = fmaf(v, v, sq[t]);
        mx[t][r] = fmaxf(mx[t][r], v);
      }
  }
  #pragma unroll
  for (int t = 0; t < 2; ++t) {
    int c = 32*w + 16*t + l15;
    #pragma unroll
    for (int r = 0; r < 4; ++r)
      maxv[(pt0 + quad*4 + r)*128 + c] = mx[t][r];
  }
  #pragma unroll
  for (int t = 0; t < 2; ++t) {
    float s = sum[t], z = sq[t];
    s += __shfl_xor(s, 16); z += __shfl_xor(z, 16);
    s += __shfl_xor(s, 32); z += __shfl_xor(z, 32);
    if (quad == 0) {
      int c = 32*w + 16*t + l15;
      atomicAdd(&SS[c], s); atomicAdd(&SQ[c], z);
    }
  }
  __syncthreads();
  if (tid < 128) { atomicAdd(&gs3[tid], SS[tid]); atomicAdd(&gq3[tid], SQ[tid]); }
}

// ------------------------------- K8 output ---------------------------------
__global__ __launch_bounds__(256) void pf_out(
    const float* __restrict__ maxv,
    const float* __restrict__ sc3, const float* __restrict__ sh3,
    float* __restrict__ out) {
  __shared__ float T[128][65];
  __shared__ float SC[128], SH[128];
  const int tid = threadIdx.x;
  const int b  = blockIdx.x >> 6;
  const int n0 = (blockIdx.x & 63) * 64;
  if (tid < 128) { SC[tid] = sc3[tid]; SH[tid] = sh3[tid]; }
  __syncthreads();
  const float4* mv4 = (const float4*)maxv;
  #pragma unroll
  for (int r = 0; r < 8; ++r) {
    int fid = r * 256 + tid;
    int nl = fid >> 5, c4 = fid & 31;
    float4 v = mv4[(b*NPTS + n0 + nl)*32 + c4];
    int c = c4 * 4;
    T[c+0][nl] = fmaf(SC[c+0], v.x, SH[c+0]);
    T[c+1][nl] = fmaf(SC[c+1], v.y, SH[c+1]);
    T[c+2][nl] = fmaf(SC[c+2], v.z, SH[c+2]);
    T[c+3][nl] = fmaf(SC[c+3], v.w, SH[c+3]);
  }
  __syncthreads();
  #pragma unroll
  for (int r = 0; r < 8; ++r) {
    int fid = r * 256 + tid;
    int c = fid >> 4, nq = fid & 15;
    float4 o;
    o.x = T[c][nq*4+0]; o.y = T[c][nq*4+1];
    o.z = T[c][nq*4+2]; o.w = T[c][nq*4+3];
    *(float4*)(out + (size_t)b*128*NPTS + (size_t)c*NPTS + n0 + nq*4) = o;
  }
}

// ------------------------------- launcher ----------------------------------
extern "C" void kernel_launch(void* const* d_in, const int* in_sizes, int n_in,
                              void* d_out, int out_size, void* d_ws, size_t ws_size,
                              hipStream_t stream) {
  const float* x   = (const float*)d_in[0];
  const float* W1  = (const float*)d_in[1];
  const float* b1  = (const float*)d_in[2];
  const float* g1  = (const float*)d_in[3];
  const float* be1 = (const float*)d_in[4];
  const float* W2  = (const float*)d_in[5];
  const float* b2  = (const float*)d_in[6];
  const float* g2  = (const float*)d_in[7];
  const float* be2 = (const float*)d_in[8];
  const float* W3  = (const float*)d_in[9];
  const float* b3  = (const float*)d_in[10];
  const float* g3  = (const float*)d_in[11];
  const float* be3 = (const float*)d_in[12];
  float* out = (float*)d_out;

  char* p = (char*)d_ws;
  float4*         xp   = (float4*)(p);                               // 256 KB
  int*            idxb = (int*)(p + 262144);                         // 1.25 MB
  float*          stats= (float*)(p + 262144 + 1310720);             // 2.5 KB
  float*          aff  = (float*)(p + 262144 + 1310720 + 2560);      // 2.5 KB
  unsigned short* wpk  = (unsigned short*)(p + 262144 + 1310720 + 5120); // 68 KB
  float*          maxv = (float*)(p + 262144 + 1310720 + 5120 + 69632);  // 8 MB

  float *mom = stats;
  float *gs2 = stats + 128, *gq2 = stats + 256;
  float *gs3 = stats + 384, *gq3 = stats + 512;
  float *sc1e = aff,        *sh1e = aff + 64;
  float *sc2e = aff + 128,  *shm2 = aff + 256;
  float *sc3  = aff + 384,  *sh3  = aff + 512;

  pf_prep    <<<64,   256, 0, stream>>>(x, xp, stats);
  pf_knn     <<<2048, 256, 0, stream>>>(xp, idxb);
  pf_mom     <<<128,  256, 0, stream>>>(xp, idxb, mom);
  pf_affine1m<<<1,    64,  0, stream>>>(mom, W1, b1, g1, be1, sc1e, sh1e);
  pf_pack    <<<52,   64,  0, stream>>>(W1, sc1e, W2, sc2e, W3, 0, wpk);
  pf_stats2  <<<1024, 256, 0, stream>>>(xp, idxb, wpk, sh1e, b2, gs2, gq2);
  pf_affine  <<<1,    128, 0, stream>>>(gs2, gq2, g2, be2, b2, 1, 128, sc2e, shm2);
  pf_pack    <<<16,   64,  0, stream>>>(W1, sc1e, W2, sc2e, W3, 1, wpk);
  pf_main    <<<1024, 256, 0, stream>>>(xp, idxb, wpk, sh1e, shm2, b3,
                                        gs3, gq3, maxv);
  pf_affine  <<<1,    128, 0, stream>>>(gs3, gq3, g3, be3, b3, 0, 128, sc3, sh3);
  pf_out     <<<256,  256, 0, stream>>>(maxv, sc3, sh3, out);
}